// Round 12
// baseline (2255.998 us; speedup 1.0000x reference)
//
#include <hip/hip_runtime.h>
#include <hip/hip_bf16.h>
#include <cstddef>

#define D 32
#define EF 64
#define NSTEPS 3

#define NSPLIT 4            // f-slices (grid.y)
#define FS (EF / NSPLIT)    // 16 f-values per slice
#define TE 4                // edges per wave
#define WAVES 8
#define BLK (WAVES * 64)    // 512 threads
#define EPB (WAVES * TE)    // 32 edges per block

__device__ __forceinline__ float sigmoidf_(float x) { return 1.0f / (1.0f + expf(-x)); }

// ---------------------------------------------------------------------------
// msg[e,o] = sum_{f,dd} ef[e,f] * h[src[e],dd] * W[f,dd*32+o]  (+ bias rows)
// scattered into a[dst[e],o] via atomics.
//
// Reassociated as:  T[e,q,o] = sum_ff ef[e,f0+ff] * B[ff][q][o]   (hot loop)
//                   msg[e,o] = sum_q h[src[e], dbase+q] * T[e,q,o] (epilogue)
//
// LAUNCH BOUNDS (the R11 lesson): R7/R8/R11 all pinned VGPR_Count to 60-64.
// 64 = 512regs/8waves-per-SIMD: the arg2=4 was evidently taken with CUDA
// semantics (min 4 BLOCKS/CU = 32 waves/CU = 8 waves/SIMD -> 64-reg hard cap),
// so T[] could never be register-resident and the compiler restructured the
// loop with extra LDS ops (VALUBusy ~46-52%, 3.3x the FMA floor).
// (512, 2): CUDA reading -> 2 blocks/CU = 4 waves/SIMD -> 128-reg budget;
// HIP waves-per-EU reading -> 256-reg budget. Either way >=128. LDS (64KB)
// independently caps residency at 2 blocks/CU, so nothing is lost.
// ---------------------------------------------------------------------------
__global__ __launch_bounds__(BLK, 2) void msg_gemm_kernel(
    const float* __restrict__ h, const float* __restrict__ efeat,
    const float* __restrict__ W, const float* __restrict__ bvec,
    const int* __restrict__ src, const int* __restrict__ dst,
    float* __restrict__ a, int E) {
  __shared__ float Blds[FS * D * D];  // [ff][dd][o], 64 KB
  const int t = threadIdx.x;
  const int f0 = blockIdx.y * FS;
  {
    // slice is contiguous: W[f0*1024 .. (f0+16)*1024)
    const float4* g4 = (const float4*)(W + (size_t)f0 * (D * D));
    float4* l4 = (float4*)Blds;
#pragma unroll
    for (int i = 0; i < (FS * D * D / 4) / BLK; ++i)  // 8 iters
      l4[t + i * BLK] = g4[t + i * BLK];
  }
  __syncthreads();

  const int wv = t >> 6;
  const int lane = t & 63;
  const int o = lane & 31;
  const int half = lane >> 5;       // dd-half: [16*half, 16*half+16)
  const int dbase = half * 16;
  const int ebase = blockIdx.x * EPB + wv * TE;
  const int sh0 = f0 & 16;          // shfl base within the loaded ef 32-half

  float hv[TE];
  float efv[TE];
  int dn[TE];
  bool ok[TE];
#pragma unroll
  for (int j = 0; j < TE; ++j) {
    const int e = ebase + j;
    ok[j] = (e < E);
    const int s = ok[j] ? src[e] : 0;
    dn[j] = ok[j] ? dst[e] : 0;
    hv[j] = ok[j] ? h[(size_t)s * D + o] : 0.0f;     // h[s][o]
    efv[j] = ok[j] ? efeat[(size_t)e * EF + (f0 & 32) + o] : 0.0f;
  }

  // Hot loop: T[j][q] += ef_f * B[ff][dbase+q][o].  Per iter: 4 bpermute
  // (uniform-index shfl) + 16 ds_read_b32 (bank=o, 2-way across halves: free)
  // vs 64 VALU FMA -> marginally VALU-bound once T is register-resident.
  float T[TE][16] = {};
  for (int ff = 0; ff < FS; ++ff) {
    float ef_f[TE];
#pragma unroll
    for (int j = 0; j < TE; ++j) ef_f[j] = __shfl(efv[j], sh0 + ff, 32);
    const float* Brow = Blds + ((size_t)(ff * D + dbase)) * D + o;
#pragma unroll
    for (int q = 0; q < 16; ++q) {
      const float bv = Brow[q * D];
#pragma unroll
      for (int j = 0; j < TE; ++j) T[j][q] += ef_f[j] * bv;
    }
  }

  if (blockIdx.y == 0) {  // fold bias rows once: epilogue multiplies by h_q
#pragma unroll
    for (int q = 0; q < 16; ++q) {
      const float bb = bvec[(dbase + q) * D + o];
#pragma unroll
      for (int j = 0; j < TE; ++j) T[j][q] += bb;
    }
  }

  // Epilogue: msg = sum_q h[s][dbase+q] * T[q]; combine dd-halves; scatter.
#pragma unroll
  for (int j = 0; j < TE; ++j) {
    float v = 0.f;
#pragma unroll
    for (int q = 0; q < 16; ++q)
      v += __shfl(hv[j], dbase + q, 32) * T[j][q];
    v += __shfl_xor(v, 32);
    if (half == 0 && ok[j]) atomicAdd(a + (size_t)dn[j] * D + o, v);
  }
}

// ---------------------------------------------------------------------------
// GRUCell: 32 lanes per node, 8 nodes per block. W matrices staged transposed
// in LDS ([k][row] so lanes o=0..31 read consecutive addresses, conflict-free).
// ---------------------------------------------------------------------------
__global__ __launch_bounds__(256) void gru_kernel(
    const float* __restrict__ a, const float* __restrict__ h,
    const float* __restrict__ W_ih, const float* __restrict__ b_ih,
    const float* __restrict__ W_hh, const float* __restrict__ b_hh,
    float* __restrict__ out, int Nn) {
  __shared__ float wi[D * 96];
  __shared__ float wh[D * 96];
  const int t = threadIdx.x;
  for (int i = t; i < 96 * D; i += 256) {
    const int row = i >> 5, k = i & 31;
    wi[k * 96 + row] = W_ih[i];
    wh[k * 96 + row] = W_hh[i];
  }
  __syncthreads();
  const int o = t & 31;
  const int n = blockIdx.x * 8 + (t >> 5);
  if (n >= Nn) return;
  const float x = a[(size_t)n * D + o];
  const float hv = h[(size_t)n * D + o];
  float air = 0.f, aiz = 0.f, ain = 0.f, ahr = 0.f, ahz = 0.f, ahn = 0.f;
#pragma unroll
  for (int k = 0; k < D; ++k) {
    const float xk = __shfl(x, k, 32);
    const float hk = __shfl(hv, k, 32);
    const float* wik = wi + k * 96;
    const float* whk = wh + k * 96;
    air += wik[o] * xk;      ahr += whk[o] * hk;
    aiz += wik[32 + o] * xk; ahz += whk[32 + o] * hk;
    ain += wik[64 + o] * xk; ahn += whk[64 + o] * hk;
  }
  const float r = sigmoidf_(air + b_ih[o] + ahr + b_hh[o]);
  const float z = sigmoidf_(aiz + b_ih[32 + o] + ahz + b_hh[32 + o]);
  const float nn = tanhf(ain + b_ih[64 + o] + r * (ahn + b_hh[64 + o]));
  out[(size_t)n * D + o] = (1.0f - z) * nn + z * hv;
}

// ---------------------------------------------------------------------------
extern "C" void kernel_launch(void* const* d_in, const int* in_sizes, int n_in,
                              void* d_out, int out_size, void* d_ws, size_t ws_size,
                              hipStream_t stream) {
  const float* feat   = (const float*)d_in[0];
  const float* efeat  = (const float*)d_in[1];
  const float* W_edge = (const float*)d_in[2];
  const float* b_edge = (const float*)d_in[3];
  const float* W_ih   = (const float*)d_in[4];
  const float* b_ih   = (const float*)d_in[5];
  const float* W_hh   = (const float*)d_in[6];
  const float* b_hh   = (const float*)d_in[7];
  const int*   src    = (const int*)d_in[8];
  const int*   dst    = (const int*)d_in[9];
  float* out = (float*)d_out;
  const int Nn = in_sizes[0] / D;
  const int Ee = in_sizes[8];

  char* ws = (char*)d_ws;
  float* a    = (float*)ws;                                    // N*D f32
  float* hbuf = (float*)(ws + (size_t)Nn * D * sizeof(float)); // N*D f32

  const dim3 blk(BLK);
  const dim3 grid((Ee + EPB - 1) / EPB, NSPLIT);

  for (int step = 0; step < NSTEPS; ++step) {
    const float* hin = (step == 0) ? feat : hbuf;
    float* hout = (step == NSTEPS - 1) ? out : hbuf;
    (void)hipMemsetAsync(a, 0, (size_t)Nn * D * sizeof(float), stream);
    msg_gemm_kernel<<<grid, blk, 0, stream>>>(
        hin, efeat, W_edge, b_edge, src, dst, a, Ee);
    gru_kernel<<<(Nn + 7) / 8, 256, 0, stream>>>(
        a, hin, W_ih, b_ih, W_hh, b_hh, hout, Nn);
  }
}

// Round 15
// 2215.091 us; speedup vs baseline: 1.0185x; 1.0185x over previous
//
#include <hip/hip_runtime.h>
#include <hip/hip_bf16.h>
#include <cstddef>

#define D 32
#define EF 64
#define NSTEPS 3

#define NSPLIT 4            // f-slices (grid.y)
#define FS (EF / NSPLIT)    // 16 f-values per slice
#define TE 8                // edges per wave (R12: raised 4->8, halves LDS/FLOP)
#define WAVES 4
#define BLK (WAVES * 64)    // 256 threads
#define EPB (WAVES * TE)    // 32 edges per block

__device__ __forceinline__ float sigmoidf_(float x) { return 1.0f / (1.0f + expf(-x)); }

__device__ __forceinline__ float readlane_f(float v, int l) {
  return __int_as_float(__builtin_amdgcn_readlane(__float_as_int(v), l));
}

// ---------------------------------------------------------------------------
// msg[e,o] = sum_{f,dd} ef[e,f] * h[src[e],dd] * W[f,dd*32+o]  (+ bias rows)
// scattered into a[dst[e],o] via atomics.
//
// T[e,q,o] = sum_ff ef[e,f0+ff]*B[ff][q][o] (hot loop); msg = sum_q h_q*T[q].
//
// R12 diagnosis: kernel is LDS-ISSUE-bound, not register-bound. Per CU-iter:
// 16 waves x (16 ds_read_b32 + 4 bpermute) x 5.8cyc = 1856 LDS cyc vs 512
// VALU cyc -> predicted 606us, observed 610us. VGPR_Count=64 across three
// variants was AGPR parking (unified file, VALU reads AGPRs directly), not
// a constraint. Fix here: TE=8 (each B dword feeds 8 FMAs, not 4) and
// readlane (VALU pipe) instead of bpermute (LDS pipe) for the wave-uniform
// ef broadcast. New balance/CU-iter: LDS 742 cyc vs VALU 512 -> ~245us.
// ---------------------------------------------------------------------------
__global__ __launch_bounds__(BLK, 2) void msg_gemm_kernel(
    const float* __restrict__ h, const float* __restrict__ efeat,
    const float* __restrict__ W, const float* __restrict__ bvec,
    const int* __restrict__ src, const int* __restrict__ dst,
    float* __restrict__ a, int E) {
  __shared__ float Blds[FS * D * D];  // [ff][dd][o], 64 KB
  const int t = threadIdx.x;
  const int f0 = blockIdx.y * FS;
  {
    // slice is contiguous: W[f0*1024 .. (f0+16)*1024)
    const float4* g4 = (const float4*)(W + (size_t)f0 * (D * D));
    float4* l4 = (float4*)Blds;
#pragma unroll
    for (int i = 0; i < (FS * D * D / 4) / BLK; ++i)  // 16 iters @ 256 thr
      l4[t + i * BLK] = g4[t + i * BLK];
  }
  __syncthreads();

  const int wv = t >> 6;
  const int lane = t & 63;
  const int o = lane & 31;
  const int half = lane >> 5;       // dd-half: [16*half, 16*half+16)
  const int dbase = half * 16;
  const int ebase = blockIdx.x * EPB + wv * TE;
  const int sh0 = f0 & 16;          // lane base within the loaded ef 32-half

  float hv[TE];
  float efv[TE];
  int dn[TE];
  bool ok[TE];
#pragma unroll
  for (int j = 0; j < TE; ++j) {
    const int e = ebase + j;
    ok[j] = (e < E);
    const int s = ok[j] ? src[e] : 0;
    dn[j] = ok[j] ? dst[e] : 0;
    hv[j] = ok[j] ? h[(size_t)s * D + o] : 0.0f;     // h[s][o]
    efv[j] = ok[j] ? efeat[(size_t)e * EF + (f0 & 32) + o] : 0.0f;
  }

  // Hot loop. Per wave-iter: 16 ds_read_b32 (bank=o, 2-way across halves:
  // free) + 8 v_readlane (VALU) + 128 FMA. Accumulators T[8][16] static-
  // indexed; AGPR parking is fine (unified RF).
  float T[TE][16] = {};
  for (int ff = 0; ff < FS; ++ff) {
    float ef_f[TE];
#pragma unroll
    for (int j = 0; j < TE; ++j) ef_f[j] = readlane_f(efv[j], sh0 + ff);
    const float* Brow = Blds + ((size_t)(ff * D + dbase)) * D + o;
#pragma unroll
    for (int q = 0; q < 16; ++q) {
      const float bv = Brow[q * D];
#pragma unroll
      for (int j = 0; j < TE; ++j) T[j][q] += ef_f[j] * bv;
    }
  }

  if (blockIdx.y == 0) {  // fold bias rows once: epilogue multiplies by h_q
#pragma unroll
    for (int q = 0; q < 16; ++q) {
      const float bb = bvec[(dbase + q) * D + o];
#pragma unroll
      for (int j = 0; j < TE; ++j) T[j][q] += bb;
    }
  }

  // Epilogue: msg = sum_q h[s][dbase+q] * T[q]; combine dd-halves; scatter.
#pragma unroll
  for (int j = 0; j < TE; ++j) {
    float v = 0.f;
#pragma unroll
    for (int q = 0; q < 16; ++q)
      v += __shfl(hv[j], dbase + q, 32) * T[j][q];
    v += __shfl_xor(v, 32);
    if (half == 0 && ok[j]) atomicAdd(a + (size_t)dn[j] * D + o, v);
  }
}

// ---------------------------------------------------------------------------
// GRUCell: 32 lanes per node, 8 nodes per block. W matrices staged transposed
// in LDS ([k][row] so lanes o=0..31 read consecutive addresses, conflict-free).
// ---------------------------------------------------------------------------
__global__ __launch_bounds__(256) void gru_kernel(
    const float* __restrict__ a, const float* __restrict__ h,
    const float* __restrict__ W_ih, const float* __restrict__ b_ih,
    const float* __restrict__ W_hh, const float* __restrict__ b_hh,
    float* __restrict__ out, int Nn) {
  __shared__ float wi[D * 96];
  __shared__ float wh[D * 96];
  const int t = threadIdx.x;
  for (int i = t; i < 96 * D; i += 256) {
    const int row = i >> 5, k = i & 31;
    wi[k * 96 + row] = W_ih[i];
    wh[k * 96 + row] = W_hh[i];
  }
  __syncthreads();
  const int o = t & 31;
  const int n = blockIdx.x * 8 + (t >> 5);
  if (n >= Nn) return;
  const float x = a[(size_t)n * D + o];
  const float hv = h[(size_t)n * D + o];
  float air = 0.f, aiz = 0.f, ain = 0.f, ahr = 0.f, ahz = 0.f, ahn = 0.f;
#pragma unroll
  for (int k = 0; k < D; ++k) {
    const float xk = __shfl(x, k, 32);
    const float hk = __shfl(hv, k, 32);
    const float* wik = wi + k * 96;
    const float* whk = wh + k * 96;
    air += wik[o] * xk;      ahr += whk[o] * hk;
    aiz += wik[32 + o] * xk; ahz += whk[32 + o] * hk;
    ain += wik[64 + o] * xk; ahn += whk[64 + o] * hk;
  }
  const float r = sigmoidf_(air + b_ih[o] + ahr + b_hh[o]);
  const float z = sigmoidf_(aiz + b_ih[32 + o] + ahz + b_hh[32 + o]);
  const float nn = tanhf(ain + b_ih[64 + o] + r * (ahn + b_hh[64 + o]));
  out[(size_t)n * D + o] = (1.0f - z) * nn + z * hv;
}

// ---------------------------------------------------------------------------
extern "C" void kernel_launch(void* const* d_in, const int* in_sizes, int n_in,
                              void* d_out, int out_size, void* d_ws, size_t ws_size,
                              hipStream_t stream) {
  const float* feat   = (const float*)d_in[0];
  const float* efeat  = (const float*)d_in[1];
  const float* W_edge = (const float*)d_in[2];
  const float* b_edge = (const float*)d_in[3];
  const float* W_ih   = (const float*)d_in[4];
  const float* b_ih   = (const float*)d_in[5];
  const float* W_hh   = (const float*)d_in[6];
  const float* b_hh   = (const float*)d_in[7];
  const int*   src    = (const int*)d_in[8];
  const int*   dst    = (const int*)d_in[9];
  float* out = (float*)d_out;
  const int Nn = in_sizes[0] / D;
  const int Ee = in_sizes[8];

  char* ws = (char*)d_ws;
  float* a    = (float*)ws;                                    // N*D f32
  float* hbuf = (float*)(ws + (size_t)Nn * D * sizeof(float)); // N*D f32

  const dim3 blk(BLK);
  const dim3 grid((Ee + EPB - 1) / EPB, NSPLIT);

  for (int step = 0; step < NSTEPS; ++step) {
    const float* hin = (step == 0) ? feat : hbuf;
    float* hout = (step == NSTEPS - 1) ? out : hbuf;
    (void)hipMemsetAsync(a, 0, (size_t)Nn * D * sizeof(float), stream);
    msg_gemm_kernel<<<grid, blk, 0, stream>>>(
        hin, efeat, W_edge, b_edge, src, dst, a, Ee);
    gru_kernel<<<(Nn + 7) / 8, 256, 0, stream>>>(
        a, hin, W_ih, b_ih, W_hh, b_hh, hout, Nn);
  }
}